// Round 14
// baseline (110.726 us; speedup 1.0000x reference)
//
#include <hip/hip_runtime.h>
#include <hip/hip_bf16.h>

#define IN_FEAT 4096
#define OUT_FEAT 4096
#define FP_FEAT 256
#define INT_FEAT 3840
#define TOKENS 4096
#define PACKED_W (INT_FEAT / 2)  // 1920

#define NT_I8 60          // int K-tiles (K=64 i8 each)
#define NT_ALL 68         // + 8 fp sub-tiles (K=32 bf16 each)

typedef __attribute__((ext_vector_type(8))) short short8;
typedef __attribute__((ext_vector_type(4))) float f32x4;
typedef __attribute__((ext_vector_type(4))) int   int32x4;

// workspace layout (bytes)
#define AQ8_OFF   0u
#define WB8_OFF   16777216u
#define AFP_OFF   33554432u
#define WFP_OFF   35651584u
#define SCALE_OFF 37748736u
#define ZERO_OFF  37765120u
#define WS_NEED   37781504u

// ------------------------------------------------- fused quantize + unpack ---
__global__ __launch_bounds__(256) void prep_kernel(
    const float* __restrict__ x,
    const int* __restrict__ int_idx_raw,
    const int* __restrict__ fp_idx_raw,
    const int* __restrict__ wpacked_raw,
    const float* __restrict__ fpw,
    const float* __restrict__ wscale,
    signed char* __restrict__ Aq8,
    __hip_bfloat16* __restrict__ Afp,
    signed char* __restrict__ Wb8,
    __hip_bfloat16* __restrict__ Wfp,
    float* __restrict__ scale_ws,
    float* __restrict__ zero_ws)
{
    const int t = threadIdx.x;
    if (blockIdx.x < TOKENS) {
        const int m = blockIdx.x;
        const float* xr = x + (size_t)m * IN_FEAT;
        const bool is64 = (int_idx_raw[1] == 0) && (int_idx_raw[3] == 0);

        float v[15];
        float mn = 1e30f, mx = -1e30f;
#pragma unroll
        for (int j = 0; j < 15; ++j) {
            int k = t + j * 256;
            int idx = is64 ? int_idx_raw[2 * k] : int_idx_raw[k];
            float f = xr[idx];
            v[j] = f;
            mn = fminf(mn, f);
            mx = fmaxf(mx, f);
        }
#pragma unroll
        for (int off = 1; off < 64; off <<= 1) {
            mn = fminf(mn, __shfl_xor(mn, off));
            mx = fmaxf(mx, __shfl_xor(mx, off));
        }
        __shared__ float smn[4], smx[4];
        int wid = t >> 6, lane = t & 63;
        if (lane == 0) { smn[wid] = mn; smx[wid] = mx; }
        __syncthreads();
        if (t == 0) {
            float rmn = fminf(fminf(smn[0], smn[1]), fminf(smn[2], smn[3]));
            float rmx = fmaxf(fmaxf(smx[0], smx[1]), fmaxf(smx[2], smx[3]));
            float sc = fmaxf((rmx - rmn) / 15.0f, 1e-8f);
            smn[0] = rmn;
            smx[0] = sc;
            scale_ws[m] = sc;
            zero_ws[m] = rmn;
        }
        __syncthreads();
        const float zero = smn[0];
        const float sc = smx[0];

        signed char* ar = Aq8 + (size_t)m * INT_FEAT;
#pragma unroll
        for (int j = 0; j < 15; ++j) {
            int k = t + j * 256;
            float q = rintf((v[j] - zero) / sc) - 8.0f;  // IEEE div+rndne == np
            q = fminf(fmaxf(q, -8.0f), 7.0f);
            ar[k] = (signed char)(int)q;                 // exact small int
        }
        int fpi = is64 ? fp_idx_raw[2 * t] : fp_idx_raw[t];
        Afp[(size_t)m * FP_FEAT + t] = __float2bfloat16(xr[fpi] / sc);
    } else {
        const int n = blockIdx.x - TOKENS;
        bool is_i32 = true;
#pragma unroll
        for (int j = 0; j < 8; ++j) {
            unsigned w = (unsigned)wpacked_raw[j];
            if (w > 0xFFu) is_i32 = false;
        }
        short* wo = (short*)(Wb8 + (size_t)n * INT_FEAT);
#pragma unroll
        for (int j = 0; j < 8; ++j) {
            int k = t + j * 256;
            if (k < PACKED_W) {
                int p = is_i32 ? wpacked_raw[(size_t)n * PACKED_W + k]
                               : ((const unsigned char*)wpacked_raw)[(size_t)n * PACKED_W + k];
                int lo = p & 15; if (lo >= 8) lo -= 16;
                int hi = (p >> 4) & 15; if (hi >= 8) hi -= 16;
                wo[k] = (short)(((unsigned char)lo) | ((unsigned short)(unsigned char)hi << 8));
            }
        }
        float wsn = wscale[n];
        Wfp[(size_t)n * FP_FEAT + t] = __float2bfloat16(fpw[(size_t)n * FP_FEAT + t] / wsn);
    }
}

// ------------------------------------------- GEMM 256x128, 2 blocks/CU ------
// Occupancy attack (r14): tile 256x128, grid 512 = 2 independent blocks/CU.
// Barrier-locked waves within a block serialize LDS-port phase vs MFMA phase
// (r10-r13 all ~3100cyc/tile); a second block with independent barriers runs
// phase-shifted on the same CU, overlapping one block's reads with the
// other's MFMA (m114 mechanism). 8 waves = 4M x 2N, per-wave out 64x64
// (acc 4x4 frags = 64 VGPR). LDS 3 buffers x (A 16KB + B 8KB) = 72KB ->
// 2 blocks/CU; launch_bounds(512,4) caps VGPR at 128 (16 waves/CU).
// Pipeline (r10-proven): per tile: {8 ds_read; stage(vt+2) 3 gloads;
// 16 MFMA; vmcnt(3); barrier}. vmcnt(3) drains stage(vt+1), keeps vt+2's 3
// in flight -- counted, never 0 until the tail. Swizzle identical to r10
// (0 conflicts measured). K-order per acc element identical to r10-r13
// -> absmax must stay bit-exact 0.1992188.

__global__ __launch_bounds__(512, 4) void gemm256_i8(
    const signed char* __restrict__ Aq8,
    const __hip_bfloat16* __restrict__ Afp,
    const signed char* __restrict__ Wb8,
    const __hip_bfloat16* __restrict__ Wfp,
    const float* __restrict__ scale_ws,
    const float* __restrict__ zero_ws,
    const float* __restrict__ wscale,
    const float* __restrict__ reduced,
    const float* __restrict__ bias,
    float* __restrict__ out)
{
    __shared__ __align__(16) char lds[73728];  // 3 x (16K A + 8K B)

    const int t = threadIdx.x;
    const int lane = t & 63, wid = t >> 6;
    const int wr = wid >> 1;                   // 0..3 (M)
    const int wc = wid & 1;                    // 0..1 (N)
    const int r16 = lane & 15;
    const int kg = lane >> 4;                  // 0..3

    // XCD-aware block swizzle (512 blocks, 8 XCDs, 64/chunk)
    const int bid = blockIdx.x;
    const int sb = (bid & 7) * 64 + (bid >> 3);
    const int tileM = (sb >> 5) * 256;         // 16 M-tiles
    const int tileN = (sb & 31) * 128;         // 32 N-tiles

    // staging geometry: A 1024 chunks (2/thread), B 512 chunks (1/thread)
    const int r0 = t >> 2, c0 = t & 3;
    const int sw0 = ((c0 ^ ((r0 >> 1) & 3)) << 4);
    const char* a8_0 = (const char*)Aq8 + (size_t)(tileM + r0) * INT_FEAT + sw0;
    const char* a8_1 = (const char*)Aq8 + (size_t)(tileM + 128 + r0) * INT_FEAT + sw0;
    const char* b8_0 = (const char*)Wb8 + (size_t)(tileN + r0) * INT_FEAT + sw0;   // r0<128
    const char* af_0 = (const char*)Afp + (size_t)(tileM + r0) * 512 + sw0;
    const char* af_1 = (const char*)Afp + (size_t)(tileM + 128 + r0) * 512 + sw0;
    const char* bf_0 = (const char*)Wfp + (size_t)(tileN + r0) * 512 + sw0;
    const int dstA0 = t << 4;                  // 0..8176
    const int dstA1 = (512 + t) << 4;          // 8192..16368
    const int dstB0 = t << 4;                  // within B region

    auto stage = [&](int vt, int bufB) {       // 3 gloads (2 A + 1 B)
        const bool i8p = vt < NT_I8;
        const int ko = i8p ? vt * 64 : (vt - NT_I8) * 64;
        const char* pa0 = (i8p ? a8_0 : af_0) + ko;
        const char* pa1 = (i8p ? a8_1 : af_1) + ko;
        const char* pb0 = (i8p ? b8_0 : bf_0) + ko;
        __builtin_amdgcn_global_load_lds(
            (const __attribute__((address_space(1))) void*)pa0,
            (__attribute__((address_space(3))) void*)(lds + bufB + dstA0), 16, 0, 0);
        __builtin_amdgcn_global_load_lds(
            (const __attribute__((address_space(1))) void*)pa1,
            (__attribute__((address_space(3))) void*)(lds + bufB + dstA1), 16, 0, 0);
        __builtin_amdgcn_global_load_lds(
            (const __attribute__((address_space(1))) void*)pb0,
            (__attribute__((address_space(3))) void*)(lds + bufB + 16384 + dstB0), 16, 0, 0);
    };

    // fragment read byte-offsets (64B rows, 16B frags, swizzled)
    int aOff[4], bOff[4];
#pragma unroll
    for (int mf = 0; mf < 4; ++mf) {
        int ra = wr * 64 + mf * 16 + r16;      // 0..255
        aOff[mf] = ra * 64 + ((((ra >> 1) & 3) ^ kg) << 4);
    }
#pragma unroll
    for (int nf = 0; nf < 4; ++nf) {
        int rb = wc * 64 + nf * 16 + r16;      // 0..127
        bOff[nf] = 16384 + rb * 64 + ((((rb >> 1) & 3) ^ kg) << 4);
    }

    int32x4 acc[4][4];
#pragma unroll
    for (int mf = 0; mf < 4; ++mf)
#pragma unroll
        for (int nf = 0; nf < 4; ++nf)
            acc[mf][nf] = (int32x4){0, 0, 0, 0};

    // prologue: stage tiles 0,1; drain tile 0 (vmcnt(3) leaves tile1 flying)
    stage(0, 0);
    stage(1, 24576);
    asm volatile("s_waitcnt vmcnt(3)" ::: "memory");
    __builtin_amdgcn_sched_barrier(0);
    __builtin_amdgcn_s_barrier();
    __builtin_amdgcn_sched_barrier(0);

    int bufB = 0;
    // ---- loop 1: 60 i8 K-tiles (exact integer accumulation) ----
    for (int vt = 0; vt < NT_I8; ++vt) {
        int32x4 bI[4], aI[4];
#pragma unroll
        for (int nf = 0; nf < 4; ++nf)                 // B first
            bI[nf] = *(const int32x4*)(lds + bufB + bOff[nf]);
#pragma unroll
        for (int mf = 0; mf < 4; ++mf)
            aI[mf] = *(const int32x4*)(lds + bufB + aOff[mf]);

        stage(vt + 2, (bufB == 0) ? 49152 : bufB - 24576);   // (vt+2)%3

        __builtin_amdgcn_s_setprio(1);
#pragma unroll
        for (int mf = 0; mf < 4; ++mf)
#pragma unroll
            for (int nf = 0; nf < 4; ++nf)
                acc[mf][nf] = __builtin_amdgcn_mfma_i32_16x16x64_i8(
                    aI[mf], bI[nf], acc[mf][nf], 0, 0, 0);
        __builtin_amdgcn_s_setprio(0);

        asm volatile("s_waitcnt vmcnt(3)" ::: "memory");
        __builtin_amdgcn_sched_barrier(0);
        __builtin_amdgcn_s_barrier();
        __builtin_amdgcn_sched_barrier(0);
        bufB = (bufB == 49152) ? 0 : bufB + 24576;
    }

    // ---- exact int32 -> f32 conversion (in place, bit-pattern reuse) ----
#pragma unroll
    for (int mf = 0; mf < 4; ++mf)
#pragma unroll
        for (int nf = 0; nf < 4; ++nf) {
            int32x4 vi = acc[mf][nf];
            f32x4 vf;
#pragma unroll
            for (int i = 0; i < 4; ++i) vf[i] = (float)vi[i];
            acc[mf][nf] = __builtin_bit_cast(int32x4, vf);
        }

    // ---- loop 2: 8 bf16 fp sub-tiles (K=32 each) ----
    for (int vt = NT_I8; vt < NT_ALL; ++vt) {
        short8 bF[4], aF[4];
#pragma unroll
        for (int nf = 0; nf < 4; ++nf)
            bF[nf] = *(const short8*)(lds + bufB + bOff[nf]);
#pragma unroll
        for (int mf = 0; mf < 4; ++mf)
            aF[mf] = *(const short8*)(lds + bufB + aOff[mf]);

        if (vt + 2 < NT_ALL)
            stage(vt + 2, (bufB == 0) ? 49152 : bufB - 24576);

        __builtin_amdgcn_s_setprio(1);
#pragma unroll
        for (int mf = 0; mf < 4; ++mf)
#pragma unroll
            for (int nf = 0; nf < 4; ++nf)
                acc[mf][nf] = __builtin_bit_cast(int32x4,
                    __builtin_amdgcn_mfma_f32_16x16x32_bf16(
                        aF[mf], bF[nf],
                        __builtin_bit_cast(f32x4, acc[mf][nf]), 0, 0, 0));
        __builtin_amdgcn_s_setprio(0);

        if (vt <= NT_ALL - 3)
            asm volatile("s_waitcnt vmcnt(3)" ::: "memory");
        else if (vt == NT_ALL - 2)
            asm volatile("s_waitcnt vmcnt(0)" ::: "memory");
        __builtin_amdgcn_sched_barrier(0);
        __builtin_amdgcn_s_barrier();
        __builtin_amdgcn_sched_barrier(0);
        bufB = (bufB == 49152) ? 0 : bufB + 24576;
    }

    // epilogue: out = sc*ws*acc + (zero + 8*sc)*reduced + bias
    const int cr4 = kg * 4;
#pragma unroll
    for (int mf = 0; mf < 4; ++mf) {
#pragma unroll
        for (int nf = 0; nf < 4; ++nf) {
            int n = tileN + wc * 64 + nf * 16 + r16;
            float ws = wscale[n];
            float rd = reduced[n];
            float bs = bias[n];
            f32x4 av = __builtin_bit_cast(f32x4, acc[mf][nf]);
#pragma unroll
            for (int i = 0; i < 4; ++i) {
                int m = tileM + wr * 64 + mf * 16 + cr4 + i;
                float sc = scale_ws[m];
                float zr = zero_ws[m];
                out[(size_t)m * OUT_FEAT + n] =
                    sc * ws * av[i]
                    + (zr + sc * 8.0f) * rd + bs;
            }
        }
    }
}

// ------------------------------------------------------------------ launch ---
extern "C" void kernel_launch(void* const* d_in, const int* in_sizes, int n_in,
                              void* d_out, int out_size, void* d_ws, size_t ws_size,
                              hipStream_t stream)
{
    const void* px = 0; const void* pw = 0; const void* pfpw = 0;
    const void* pii = 0; const void* pfi = 0;
    const void* p4096[3] = {0, 0, 0}; int n4096 = 0;
    for (int i = 0; i < n_in; ++i) {
        switch (in_sizes[i]) {
            case 16777216: px = d_in[i]; break;
            case 7864320:  pw = d_in[i]; break;
            case 1048576:  pfpw = d_in[i]; break;
            case 3840:     pii = d_in[i]; break;
            case 256:      pfi = d_in[i]; break;
            case 4096:     if (n4096 < 3) p4096[n4096++] = d_in[i]; break;
            default: break;
        }
    }
    if (!px || !pw || !pfpw || !pii || !pfi || n4096 != 3) return;

    const float* x       = (const float*)px;
    const int*   wpacked = (const int*)pw;
    const float* wscale  = (const float*)p4096[0];
    const float* reduced = (const float*)p4096[1];
    const float* bias    = (const float*)p4096[2];
    const float* fpw     = (const float*)pfpw;
    const int*   int_idx = (const int*)pii;
    const int*   fp_idx  = (const int*)pfi;
    float*       out     = (float*)d_out;

    if (ws_size < (size_t)WS_NEED) return;

    char* ws = (char*)d_ws;
    signed char*    Aq8 = (signed char*)(ws + AQ8_OFF);
    signed char*    Wb8 = (signed char*)(ws + WB8_OFF);
    __hip_bfloat16* Afp = (__hip_bfloat16*)(ws + AFP_OFF);
    __hip_bfloat16* Wfp = (__hip_bfloat16*)(ws + WFP_OFF);
    float* scale_ws     = (float*)(ws + SCALE_OFF);
    float* zero_ws      = (float*)(ws + ZERO_OFF);

    prep_kernel<<<TOKENS + OUT_FEAT, 256, 0, stream>>>(
        x, int_idx, fp_idx, wpacked, fpw, wscale,
        Aq8, Afp, Wb8, Wfp, scale_ws, zero_ws);
    gemm256_i8<<<512, 512, 0, stream>>>(Aq8, Afp, Wb8, Wfp,
                                        scale_ws, zero_ws,
                                        wscale, reduced, bias, out);
}